// Round 2
// baseline (2668.026 us; speedup 1.0000x reference)
//
#include <hip/hip_runtime.h>

#define NN 30000
#define GG 2000
#define HH 128
#define ZZ 20
#define SS 10
#define EE 960000
#define VEPS 1e-4f

// ---------------------------------------------------------------- zero fill
__global__ void k_zero(float* __restrict__ p, int n) {
    int i = blockIdx.x * 256 + threadIdx.x;
    if (i < n) p[i] = 0.f;
}

// ---------------------------------------------------------------- K1: h1 = relu(log1p(x)@W0+b0), rowsum(x)
// Simple: 4 rows/block, 256 threads. Threads 0..127 = cols (kh=0: k 0..999),
// threads 128..255 same cols (kh=1: k 1000..1999). Combine halves via LDS.
__global__ __launch_bounds__(256) void k1(const float* __restrict__ x,
        const float* __restrict__ W0, const float* __restrict__ b0,
        float* __restrict__ h1, float* __restrict__ rowsum) {
    __shared__ float xl[4][2000];
    __shared__ float red[256];
    int tid = threadIdx.x;
    int row0 = blockIdx.x * 4;
    // stage 4 rows (log1p) + per-row rowsum of raw x
    for (int r = 0; r < 4; ++r) {
        float ps = 0.f;
        const float4* xr4 = (const float4*)(x + (size_t)(row0 + r) * GG);
        for (int i = tid; i < 500; i += 256) {
            float4 v = xr4[i];
            ps += v.x + v.y + v.z + v.w;
            xl[r][4 * i + 0] = log1pf(v.x);
            xl[r][4 * i + 1] = log1pf(v.y);
            xl[r][4 * i + 2] = log1pf(v.z);
            xl[r][4 * i + 3] = log1pf(v.w);
        }
        red[tid] = ps;
        __syncthreads();
        for (int s = 128; s > 0; s >>= 1) {
            if (tid < s) red[tid] += red[tid + s];
            __syncthreads();
        }
        if (tid == 0) rowsum[row0 + r] = red[0];
        __syncthreads();
    }
    int c = tid & 127, kh = tid >> 7;
    float acc[4] = {0.f, 0.f, 0.f, 0.f};
    for (int k4 = kh * 250; k4 < kh * 250 + 250; ++k4) {
        float w0 = W0[(size_t)(4 * k4 + 0) * HH + c];
        float w1 = W0[(size_t)(4 * k4 + 1) * HH + c];
        float w2 = W0[(size_t)(4 * k4 + 2) * HH + c];
        float w3 = W0[(size_t)(4 * k4 + 3) * HH + c];
#pragma unroll
        for (int r = 0; r < 4; ++r) {
            float4 xv = *(const float4*)&xl[r][4 * k4];
            acc[r] += xv.x * w0 + xv.y * w1 + xv.z * w2 + xv.w * w3;
        }
    }
    for (int r = 0; r < 4; ++r) {
        __syncthreads();
        red[tid] = acc[r];
        __syncthreads();
        if (tid < 128) {
            float v = red[tid] + red[tid + 128] + b0[c];
            h1[(size_t)(row0 + r) * HH + c] = fmaxf(v, 0.f);
        }
    }
}

// ---------------------------------------------------------------- K2: per-row encoder tail + GAT projections
// One row per block, 128 threads. h2 kept in LDS only.
__global__ __launch_bounds__(128) void k2(
        const float* __restrict__ h1,
        const float* __restrict__ W1, const float* __restrict__ b1,
        const float* __restrict__ Wm, const float* __restrict__ bm,
        const float* __restrict__ Wv, const float* __restrict__ bvv,
        const float* __restrict__ eps_z,
        const float* __restrict__ gmWl, const float* __restrict__ gmbl,
        const float* __restrict__ gmWr, const float* __restrict__ gmbr,
        const float* __restrict__ gvWl, const float* __restrict__ gvbl,
        const float* __restrict__ gvWr, const float* __restrict__ gvbr,
        float* __restrict__ z, float* __restrict__ xlm, float* __restrict__ xrm,
        float* __restrict__ xlv, float* __restrict__ xrv) {
    __shared__ float h1s[128], h2s[128], qm[20], qv[20];
    int row = blockIdx.x, tid = threadIdx.x;
    h1s[tid] = h1[(size_t)row * HH + tid];
    __syncthreads();
    float a = b1[tid];
    for (int k = 0; k < 128; ++k) a += h1s[k] * W1[k * HH + tid];
    h2s[tid] = fmaxf(a, 0.f);
    __syncthreads();
    if (tid < 20) {
        float s = bm[tid];
        for (int k = 0; k < 128; ++k) s += h2s[k] * Wm[k * ZZ + tid];
        qm[tid] = s;
    } else if (tid >= 64 && tid < 84) {
        int j = tid - 64;
        float s = bvv[j];
        for (int k = 0; k < 128; ++k) s += h2s[k] * Wv[k * ZZ + j];
        qv[j] = expf(s) + VEPS;
    }
    __syncthreads();
    if (tid < 20) {
        z[(size_t)row * ZZ + tid] = qm[tid] + sqrtf(qv[tid]) * eps_z[(size_t)row * ZZ + tid];
    } else if (tid >= 64 && tid < 104) {
        int t = tid - 64;
        int which = t / 10, j = t % 10;
        const float* W = which == 0 ? gmWl : which == 1 ? gmWr : which == 2 ? gvWl : gvWr;
        const float* bb = which == 0 ? gmbl : which == 1 ? gmbr : which == 2 ? gvbl : gvbr;
        float s = bb[j];
#pragma unroll
        for (int k = 0; k < 10; ++k) s += qm[10 + k] * W[k * SS + j];
        float* op = which == 0 ? xlm : which == 1 ? xrm : which == 2 ? xlv : xrv;
        op[(size_t)row * SS + j] = s;
    }
}

// ---------------------------------------------------------------- K5: edge pass (both heads), atomics.
// segment_max dropped: alpha = exp(e)/sum(exp(e)) is exact (|e| << 1 here).
__global__ __launch_bounds__(256) void k5(const int* __restrict__ ei,
        const float* __restrict__ xlm, const float* __restrict__ xrm,
        const float* __restrict__ xlv, const float* __restrict__ xrv,
        const float* __restrict__ gm_att, const float* __restrict__ gv_att,
        float* __restrict__ s_m, float* __restrict__ s_v,
        float* __restrict__ num_m, float* __restrict__ num_v) {
    int e = blockIdx.x * 256 + threadIdx.x;
    if (e >= EE) return;
    int s = ei[e];
    int d = ei[EE + e];
    float xls[10], em = 0.f;
#pragma unroll
    for (int j = 0; j < 10; ++j) {
        xls[j] = xlm[s * SS + j];
        float t = xls[j] + xrm[d * SS + j];
        t = t > 0.f ? t : 0.2f * t;
        em += t * gm_att[j];
    }
    float eem = expf(em);
    atomicAdd(&s_m[d], eem);
#pragma unroll
    for (int j = 0; j < 10; ++j) atomicAdd(&num_m[d * SS + j], eem * xls[j]);

    float xlsv[10], ev = 0.f;
#pragma unroll
    for (int j = 0; j < 10; ++j) {
        xlsv[j] = xlv[s * SS + j];
        float t = xlsv[j] + xrv[d * SS + j];
        t = t > 0.f ? t : 0.2f * t;
        ev += t * gv_att[j];
    }
    float eev = expf(ev);
    atomicAdd(&s_v[d], eev);
#pragma unroll
    for (int j = 0; j < 10; ++j) atomicAdd(&num_v[d * SS + j], eev * xlsv[j]);
}

// ---------------------------------------------------------------- K6a: build z_all (N x 30), one thread/element
__global__ __launch_bounds__(256) void k6a(
        const float* __restrict__ s_m, const float* __restrict__ s_v,
        const float* __restrict__ num_m, const float* __restrict__ num_v,
        const float* __restrict__ gm_bias, const float* __restrict__ gv_bias,
        const float* __restrict__ eps_gat, const float* __restrict__ z,
        float* __restrict__ zall) {
    int i = blockIdx.x * 256 + threadIdx.x;
    if (i >= NN * 30) return;
    int n = i / 30, j = i % 30;
    float v;
    if (j < 10) {
        float qgm = num_m[n * SS + j] / (s_m[n] + 1e-16f) + gm_bias[j];
        float rv = num_v[n * SS + j] / (s_v[n] + 1e-16f) + gv_bias[j];
        float qgv = expf(rv) + VEPS;
        v = qgm + sqrtf(qgv) * eps_gat[n * SS + j];
    } else {
        v = z[(size_t)n * ZZ + (j - 10)];
    }
    zall[i] = v;
}

// ---------------------------------------------------------------- K6b: hd = relu(LN(z_all@decW0+b0)), 1 row/block
__global__ __launch_bounds__(128) void k6b(const float* __restrict__ zall,
        const float* __restrict__ W0, const float* __restrict__ b0,
        float* __restrict__ hd) {
    __shared__ float zs[30];
    __shared__ float r1[128], r2[128];
    int row = blockIdx.x, tid = threadIdx.x;
    if (tid < 30) zs[tid] = zall[(size_t)row * 30 + tid];
    __syncthreads();
    float a = b0[tid];
#pragma unroll
    for (int k = 0; k < 30; ++k) a += zs[k] * W0[k * HH + tid];
    r1[tid] = a;
    r2[tid] = a * a;
    __syncthreads();
    for (int s = 64; s > 0; s >>= 1) {
        if (tid < s) { r1[tid] += r1[tid + s]; r2[tid] += r2[tid + s]; }
        __syncthreads();
    }
    float mean = r1[0] * (1.f / 128.f);
    float var = r2[0] * (1.f / 128.f) - mean * mean;
    float hn = (a - mean) / sqrtf(var + 1e-5f);
    hd[(size_t)row * HH + tid] = fmaxf(hn, 0.f);
}

// ---------------------------------------------------------------- K7: logits = hd@Ws+bs, 8 rows/block streaming
__global__ __launch_bounds__(256) void k7(const float* __restrict__ hd,
        const float* __restrict__ Ws, const float* __restrict__ bs,
        float* __restrict__ out) {
    __shared__ float hds[128][8];   // transposed: hds[k][r]
    int tid = threadIdx.x;
    int row0 = blockIdx.x * 8;
    for (int i = tid; i < 1024; i += 256) {
        int r = i >> 7, k = i & 127;
        hds[k][r] = hd[(size_t)(row0 + r) * HH + k];
    }
    __syncthreads();
    for (int c = tid; c < GG; c += 256) {
        float acc[8] = {};
        for (int k = 0; k < 128; ++k) {
            float w = Ws[(size_t)k * GG + c];
            float4 ha = *(const float4*)&hds[k][0];
            float4 hb = *(const float4*)&hds[k][4];
            acc[0] += ha.x * w; acc[1] += ha.y * w; acc[2] += ha.z * w; acc[3] += ha.w * w;
            acc[4] += hb.x * w; acc[5] += hb.y * w; acc[6] += hb.z * w; acc[7] += hb.w * w;
        }
        float bb = bs[c];
#pragma unroll
        for (int r = 0; r < 8; ++r) out[(size_t)(row0 + r) * GG + c] = acc[r] + bb;
    }
}

// ---------------------------------------------------------------- K8: out = rowsum * softmax(out), 1 row/block
__global__ __launch_bounds__(256) void k8(float* __restrict__ out,
                                          const float* __restrict__ rowsum) {
    __shared__ float red[256];
    int row = blockIdx.x, tid = threadIdx.x;
    float* rowp = out + (size_t)row * GG;
    float m = -1e30f;
    for (int c = tid; c < GG; c += 256) m = fmaxf(m, rowp[c]);
    red[tid] = m;
    __syncthreads();
    for (int s = 128; s > 0; s >>= 1) {
        if (tid < s) red[tid] = fmaxf(red[tid], red[tid + s]);
        __syncthreads();
    }
    m = red[0];
    __syncthreads();
    float ssum = 0.f;
    for (int c = tid; c < GG; c += 256) ssum += expf(rowp[c] - m);
    red[tid] = ssum;
    __syncthreads();
    for (int s = 128; s > 0; s >>= 1) {
        if (tid < s) red[tid] += red[tid + s];
        __syncthreads();
    }
    float scale = rowsum[row] / red[0];
    for (int c = tid; c < GG; c += 256) rowp[c] = scale * expf(rowp[c] - m);
}

// ---------------------------------------------------------------- launcher
extern "C" void kernel_launch(void* const* d_in, const int* in_sizes, int n_in,
                              void* d_out, int out_size, void* d_ws, size_t ws_size,
                              hipStream_t stream) {
    const float* x = (const float*)d_in[0];
    const int* ei = (const int*)d_in[1];
    const float* eps_z = (const float*)d_in[3];
    const float* eps_gat = (const float*)d_in[4];
    const float* enc_W0 = (const float*)d_in[5];
    const float* enc_b0 = (const float*)d_in[6];
    const float* enc_W1 = (const float*)d_in[7];
    const float* enc_b1 = (const float*)d_in[8];
    const float* enc_Wm = (const float*)d_in[9];
    const float* enc_bm = (const float*)d_in[10];
    const float* enc_Wv = (const float*)d_in[11];
    const float* enc_bv = (const float*)d_in[12];
    const float* gm_Wl = (const float*)d_in[13];
    const float* gm_bl = (const float*)d_in[14];
    const float* gm_Wr = (const float*)d_in[15];
    const float* gm_br = (const float*)d_in[16];
    const float* gm_att = (const float*)d_in[17];
    const float* gm_bias = (const float*)d_in[18];
    const float* gv_Wl = (const float*)d_in[19];
    const float* gv_bl = (const float*)d_in[20];
    const float* gv_Wr = (const float*)d_in[21];
    const float* gv_br = (const float*)d_in[22];
    const float* gv_att = (const float*)d_in[23];
    const float* gv_bias = (const float*)d_in[24];
    const float* dec_W0 = (const float*)d_in[25];
    const float* dec_b0 = (const float*)d_in[26];
    const float* dec_Ws = (const float*)d_in[27];
    const float* dec_bs = (const float*)d_in[28];

    float* ws = (float*)d_ws;
    float* rowsum = ws;                   //    30000
    float* h1     = ws + 30000;           // 3840000  (reused as hd after k2)
    float* zbuf   = ws + 3870000;         //  600000
    float* xlm    = ws + 4470000;         //  300000 (stride 10)
    float* xrm    = ws + 4770000;         //  300000
    float* xlv    = ws + 5070000;         //  300000
    float* xrv    = ws + 5370000;         //  300000
    float* s_m    = ws + 5670000;         //   30000
    float* s_v    = ws + 5700000;         //   30000
    float* num_m  = ws + 5730000;         //  300000
    float* num_v  = ws + 6030000;         //  300000
    float* zall   = ws + 6330000;         //  900000   (end: 7230000 = 28.9 MB)
    float* hd     = h1;                   // alias: h1 dead after k2
    float* out    = (float*)d_out;

    k_zero<<<(660000 + 255) / 256, 256, 0, stream>>>(s_m, 660000);
    k1<<<NN / 4, 256, 0, stream>>>(x, enc_W0, enc_b0, h1, rowsum);
    k2<<<NN, 128, 0, stream>>>(h1, enc_W1, enc_b1, enc_Wm, enc_bm, enc_Wv, enc_bv,
                               eps_z, gm_Wl, gm_bl, gm_Wr, gm_br,
                               gv_Wl, gv_bl, gv_Wr, gv_br,
                               zbuf, xlm, xrm, xlv, xrv);
    k5<<<EE / 256, 256, 0, stream>>>(ei, xlm, xrm, xlv, xrv, gm_att, gv_att,
                                     s_m, s_v, num_m, num_v);
    k6a<<<(NN * 30 + 255) / 256, 256, 0, stream>>>(s_m, s_v, num_m, num_v,
                                                   gm_bias, gv_bias, eps_gat, zbuf, zall);
    k6b<<<NN, 128, 0, stream>>>(zall, dec_W0, dec_b0, hd);
    k7<<<NN / 8, 256, 0, stream>>>(hd, dec_Ws, dec_bs, out);
    k8<<<NN, 256, 0, stream>>>(out, rowsum);
}